// Round 3
// baseline (708.668 us; speedup 1.0000x reference)
//
#include <hip/hip_runtime.h>
#include <hip/hip_bf16.h>

typedef _Float16 f16x8 __attribute__((ext_vector_type(8)));
typedef float f32x4 __attribute__((ext_vector_type(4)));

#define BIAS 32.0f       // makes all packed values positive (|dot| <= ~8)
#define TAU 0.025f       // margin below which we rescue in exact f32 (10-sigma budget)
#define TAU_MASK 0.05f   // best-value floor (guards masked-proto edge case)

__device__ __forceinline__ unsigned umax_(unsigned a, unsigned b) { return a > b ? a : b; }
__device__ __forceinline__ unsigned umin_(unsigned a, unsigned b) { return a < b ? a : b; }

// ---------------- kernel 1: q[m] = (counts[m] > 0) ? 1/||p_m|| : 0 ----------------
__global__ __launch_bounds__(64) void proto_qnorm_kernel(
    const float* __restrict__ P, const int* __restrict__ counts,
    float* __restrict__ q, int M, int Dd) {
  int m = blockIdx.x;
  int lane = threadIdx.x;
  float s = 0.f;
  for (int k = lane * 4; k < Dd; k += 256) {
    float4 v = *reinterpret_cast<const float4*>(P + (size_t)m * Dd + k);
    s += v.x * v.x + v.y * v.y + v.z * v.z + v.w * v.w;
  }
  for (int off = 32; off > 0; off >>= 1) s += __shfl_xor(s, off, 64);
  if (lane == 0) q[m] = (counts[m] > 0) ? (1.0f / sqrtf(s)) : 0.0f;
}

// ---------------- kernel 2: fp16 MFMA screen with packed top-2 + margin flag ----------------
// Block: 512 threads (8 waves as 4 row-groups x 2 col-groups). BM=256 rows.
// A (E-tile, fp16, full K=256) staged ONCE into 128KB LDS, XOR-swizzled.
// B (P-hat = P * q, fp16) streamed per (pt,kc) into 32KB LDS.
__global__ __launch_bounds__(512, 2) void screen_kernel(
    const float* __restrict__ E, const float* __restrict__ P,
    const float* __restrict__ q, int* __restrict__ out) {
  __shared__ __align__(16) unsigned char ldsA[131072];  // 256 rows x 512B (fp16 K=256)
  __shared__ __align__(16) unsigned char ldsB[32768];   // 256 protos x 128B (fp16 K=64)

  const int tid = threadIdx.x;
  const int wave = tid >> 6;
  const int lane = tid & 63;
  const int wr = wave >> 1;      // 0..3: row group of 64
  const int wc = wave & 1;       // 0..1: col group of 128
  const int g = lane >> 4;       // 0..3
  const int c = lane & 15;
  const int blockRow = blockIdx.x * 256;

  // ---- stage A once: E[blockRow..+256][0..256) f32 -> fp16, swizzled ----
#pragma unroll
  for (int u = 0; u < 16; ++u) {
    int unit = u * 512 + tid;     // 0..8191 = 256 rows x 32 slots(16B)
    int row = unit >> 5, slot = unit & 31;
    const float* src = E + (size_t)(blockRow + row) * 256 + slot * 8;
    float4 v0 = *reinterpret_cast<const float4*>(src);
    float4 v1 = *reinterpret_cast<const float4*>(src + 4);
    f16x8 h;
    h[0] = (_Float16)v0.x; h[1] = (_Float16)v0.y; h[2] = (_Float16)v0.z; h[3] = (_Float16)v0.w;
    h[4] = (_Float16)v1.x; h[5] = (_Float16)v1.y; h[6] = (_Float16)v1.z; h[7] = (_Float16)v1.w;
    int byte = (row * 512 + slot * 16) ^ ((row & 7) << 4);
    *reinterpret_cast<f16x8*>(ldsA + byte) = h;
  }

  // packed top-2 state: 16 rows per lane (rows = wr*64 + fr*16 + g*4 + reg)
  unsigned t1[16], t2[16];
#pragma unroll
  for (int s = 0; s < 16; ++s) { t1[s] = 0u; t2[s] = 0u; }

  for (int pt = 0; pt < 4; ++pt) {
    f32x4 acc[4][8];
#pragma unroll
    for (int fr = 0; fr < 4; ++fr)
#pragma unroll
      for (int fc = 0; fc < 8; ++fc) acc[fr][fc] = (f32x4){BIAS, BIAS, BIAS, BIAS};

    for (int kc = 0; kc < 4; ++kc) {
      __syncthreads();  // previous users of ldsB done (also covers A-stage first time)
      // ---- stage B: P[pt*256..+256)[kc*64..+64) * q -> fp16, swizzled ----
#pragma unroll
      for (int u = 0; u < 4; ++u) {
        int unit = u * 512 + tid;   // 0..2047 = 256 protos x 8 slots(16B)
        int prow = unit >> 3, slot = unit & 7;
        int m = pt * 256 + prow;
        const float* src = P + (size_t)m * 256 + kc * 64 + slot * 8;
        float qm = q[m];
        float4 v0 = *reinterpret_cast<const float4*>(src);
        float4 v1 = *reinterpret_cast<const float4*>(src + 4);
        f16x8 h;
        h[0] = (_Float16)(v0.x * qm); h[1] = (_Float16)(v0.y * qm);
        h[2] = (_Float16)(v0.z * qm); h[3] = (_Float16)(v0.w * qm);
        h[4] = (_Float16)(v1.x * qm); h[5] = (_Float16)(v1.y * qm);
        h[6] = (_Float16)(v1.z * qm); h[7] = (_Float16)(v1.w * qm);
        int byte = (prow * 128 + slot * 16) ^ ((prow & 7) << 4);
        *reinterpret_cast<f16x8*>(ldsB + byte) = h;
      }
      __syncthreads();

      // ---- MFMA: 2 k-steps x (4 fr x 8 fc) ----
#pragma unroll
      for (int ks = 0; ks < 2; ++ks) {
        f16x8 af[4], bf[8];
#pragma unroll
        for (int fr = 0; fr < 4; ++fr) {
          int row = wr * 64 + fr * 16 + c;
          int byte = (row * 512 + kc * 128 + ks * 64 + g * 16) ^ ((row & 7) << 4);
          af[fr] = *reinterpret_cast<const f16x8*>(ldsA + byte);
        }
#pragma unroll
        for (int fc = 0; fc < 8; ++fc) {
          int prow = wc * 128 + fc * 16 + c;
          int byte = (prow * 128 + ks * 64 + g * 16) ^ ((prow & 7) << 4);
          bf[fc] = *reinterpret_cast<const f16x8*>(ldsB + byte);
        }
#pragma unroll
        for (int fr = 0; fr < 4; ++fr)
#pragma unroll
          for (int fc = 0; fc < 8; ++fc)
            acc[fr][fc] = __builtin_amdgcn_mfma_f32_16x16x32_f16(af[fr], bf[fc], acc[fr][fc], 0, 0, 0);
      }
    }

    // ---- fold: pack (value | 1023-m) and update top-2 ----
#pragma unroll
    for (int fc = 0; fc < 8; ++fc) {
      unsigned mpack = (unsigned)(1023 - (pt * 256 + wc * 128 + fc * 16 + c));
#pragma unroll
      for (int fr = 0; fr < 4; ++fr)
#pragma unroll
        for (int reg = 0; reg < 4; ++reg) {
          int s = fr * 4 + reg;
          unsigned k = (__float_as_uint(acc[fr][fc][reg]) & 0xFFFFFC00u) | mpack;
          unsigned lo = umin_(k, t1[s]);
          t1[s] = umax_(t1[s], k);
          t2[s] = umax_(t2[s], lo);
        }
    }
  }

  // ---- cross-lane top-2 merge over the 16 lanes sharing each row ----
#pragma unroll
  for (int s = 0; s < 16; ++s) {
#pragma unroll
    for (int off = 1; off <= 8; off <<= 1) {
      unsigned o1 = __shfl_xor(t1[s], off);
      unsigned o2 = __shfl_xor(t2[s], off);
      unsigned lo = umin_(t1[s], o1);
      t1[s] = umax_(t1[s], o1);
      t2[s] = umax_(umax_(t2[s], o2), lo);
    }
  }

  __syncthreads();  // everyone done reading ldsA/ldsB -> reuse ldsA for merge
  unsigned* mg = reinterpret_cast<unsigned*>(ldsA);  // [256 rows][2 wc][2]
  if (c == 0) {
#pragma unroll
    for (int s = 0; s < 16; ++s) {
      int row = wr * 64 + (s >> 2) * 16 + g * 4 + (s & 3);
      mg[(row * 2 + wc) * 2 + 0] = t1[s];
      mg[(row * 2 + wc) * 2 + 1] = t2[s];
    }
  }
  __syncthreads();
  if (tid < 256) {
    unsigned a1 = mg[(tid * 2 + 0) * 2 + 0], a2 = mg[(tid * 2 + 0) * 2 + 1];
    unsigned b1 = mg[(tid * 2 + 1) * 2 + 0], b2 = mg[(tid * 2 + 1) * 2 + 1];
    unsigned lo = umin_(a1, b1);
    unsigned T1 = umax_(a1, b1);
    unsigned T2 = umax_(umax_(a2, b2), lo);
    int m = 1023 - (int)(T1 & 1023u);
    float v1 = __uint_as_float(T1 & 0xFFFFFC00u);
    float v2 = __uint_as_float(T2 & 0xFFFFFC00u);
    bool flag = ((v1 - v2) < TAU) || ((v1 - BIAS) < TAU_MASK);
    out[blockRow + tid] = flag ? -1 : m;
  }
}

// ---------------- kernel 3: exact f32 rescue for flagged rows ----------------
// BIT-IDENTICAL accumulation to the verified round-1 f32 kernel: per (row,proto)
// one continuous fmaf chain over k=0..255 ascending (chain CONTINUES across the
// two K-halves via part[] -- not partial-sum addition), then v = acc*q, ties to
// the smaller proto index.
__global__ __launch_bounds__(256) void rescue_kernel(
    const float* __restrict__ E, const float* __restrict__ P,
    const float* __restrict__ q, int* __restrict__ out) {
  __shared__ float Pl[256][132];   // 256 protos x 128 k (f32), padded stride
  __shared__ float Er[8][128];
  __shared__ float part[8][256];
  __shared__ int list[128];
  __shared__ int cnt;
  __shared__ float redv[8][4];
  __shared__ int redm[8][4];
  __shared__ float bestv[8];
  __shared__ int besti[8];

  const int tid = threadIdx.x;
  const int base = blockIdx.x * 128;
  if (tid == 0) cnt = 0;
  __syncthreads();
  if (tid < 128 && out[base + tid] < 0) {
    int p = atomicAdd(&cnt, 1);
    list[p] = base + tid;
  }
  __syncthreads();
  const int nf = cnt;
  if (nf == 0) return;

  for (int b = 0; b < nf; b += 8) {
    const int nb = min(8, nf - b);
    if (tid < 8) { bestv[tid] = -3.0e38f; besti[tid] = 0; }
    for (int pq = 0; pq < 4; ++pq) {           // proto quarter: 256 protos
#pragma unroll
      for (int rb = 0; rb < 8; ++rb) part[rb][tid] = 0.0f;  // own slot only
      for (int kh = 0; kh < 2; ++kh) {         // K half: 128 k
        __syncthreads();                        // prior readers of Pl/Er done
        for (int u = 0; u < 32; ++u) {          // stage Pl: 8192 float4
          int unit = u * 256 + tid;
          int prow = unit >> 5, k4 = unit & 31;
          *reinterpret_cast<float4*>(&Pl[prow][k4 * 4]) =
              *reinterpret_cast<const float4*>(P + (size_t)(pq * 256 + prow) * 256 + kh * 128 + k4 * 4);
        }
        for (int u = 0; u < 4; ++u) {           // stage Er for up to 8 rows
          int unit = u * 256 + tid;
          int rb = unit >> 7, k = unit & 127;
          if (rb < nb)
            Er[rb][k] = E[(size_t)list[b + rb] * 256 + kh * 128 + k];
        }
        __syncthreads();
        for (int rb = 0; rb < nb; ++rb) {       // thread = proto (pq*256 + tid)
          float acc = part[rb][tid];             // CONTINUE the chain (bit-identical to r1)
#pragma unroll
          for (int k4 = 0; k4 < 32; ++k4) {
            float4 pv = *reinterpret_cast<const float4*>(&Pl[tid][k4 * 4]);
            float4 ev = *reinterpret_cast<const float4*>(&Er[rb][k4 * 4]);
            acc = fmaf(pv.x, ev.x, acc); acc = fmaf(pv.y, ev.y, acc);
            acc = fmaf(pv.z, ev.z, acc); acc = fmaf(pv.w, ev.w, acc);
          }
          part[rb][tid] = acc;                   // own slot
        }
      }
      // reduce this pq's 256 protos per row
      for (int rb = 0; rb < nb; ++rb) {
        int m = pq * 256 + tid;
        float qm = q[m];
        float v = (qm > 0.f) ? part[rb][tid] * qm : -1.0e30f;
        int mi = m;
        for (int off = 32; off > 0; off >>= 1) {
          float ov = __shfl_xor(v, off);
          int om = __shfl_xor(mi, off);
          if (ov > v || (ov == v && om < mi)) { v = ov; mi = om; }
        }
        if ((tid & 63) == 0) { redv[rb][tid >> 6] = v; redm[rb][tid >> 6] = mi; }
      }
      __syncthreads();
      if (tid < 8 && tid < nb) {
        float v = redv[tid][0]; int mi = redm[tid][0];
#pragma unroll
        for (int w = 1; w < 4; ++w) {
          float ov = redv[tid][w]; int om = redm[tid][w];
          if (ov > v || (ov == v && om < mi)) { v = ov; mi = om; }
        }
        if (v > bestv[tid] || (v == bestv[tid] && mi < besti[tid])) {
          bestv[tid] = v; besti[tid] = mi;
        }
      }
      __syncthreads();
    }
    if (tid < nb) out[list[b + tid]] = besti[tid];
    __syncthreads();
  }
}

extern "C" void kernel_launch(void* const* d_in, const int* in_sizes, int n_in,
                              void* d_out, int out_size, void* d_ws, size_t ws_size,
                              hipStream_t stream) {
  const float* E = (const float*)d_in[0];
  const float* P = (const float*)d_in[1];
  const int* counts = (const int*)d_in[2];
  const int M = in_sizes[2];            // 1024
  const int Dd = in_sizes[1] / M;       // 256
  const int N = in_sizes[0] / Dd;       // 65536
  float* q = (float*)d_ws;              // M floats of scratch (4KB)
  int* out = (int*)d_out;

  proto_qnorm_kernel<<<M, 64, 0, stream>>>(P, counts, q, M, Dd);
  screen_kernel<<<N / 256, 512, 0, stream>>>(E, P, q, out);
  rescue_kernel<<<N / 128, 256, 0, stream>>>(E, P, q, out);
}

// Round 4
// 190.649 us; speedup vs baseline: 3.7171x; 3.7171x over previous
//
#include <hip/hip_runtime.h>
#include <hip/hip_bf16.h>

typedef _Float16 f16x8 __attribute__((ext_vector_type(8)));
typedef float f32x4 __attribute__((ext_vector_type(4)));

#define TAU 1e-4f   // margin below which we rescue in exact f32 (~100 sigma of split-fp16 noise)

// ---------------- kernel 1: q[m] = (counts[m] > 0) ? 1/||p_m|| : 0 ; zero worklist count ----------------
__global__ __launch_bounds__(64) void proto_qnorm_kernel(
    const float* __restrict__ P, const int* __restrict__ counts,
    float* __restrict__ q, int* __restrict__ wcount, int M, int Dd) {
  if (blockIdx.x == 0 && threadIdx.x == 0) *wcount = 0;
  int m = blockIdx.x;
  int lane = threadIdx.x;
  float s = 0.f;
  for (int k = lane * 4; k < Dd; k += 256) {
    float4 v = *reinterpret_cast<const float4*>(P + (size_t)m * Dd + k);
    s += v.x * v.x + v.y * v.y + v.z * v.z + v.w * v.w;
  }
  for (int off = 32; off > 0; off >>= 1) s += __shfl_xor(s, off, 64);
  if (lane == 0) q[m] = (counts[m] > 0) ? (1.0f / sqrtf(s)) : 0.0f;
}

// ---------------- kernel 2: split-fp16 MFMA screen (3-term Markidis) + full-precision top-2 ----------------
// Block: 512 threads = 8 waves (2 row-groups x 4 col-groups). BM=128 rows.
// A: E split into (hi,lo) fp16, full K=256, resident in 128KB LDS, XOR-swizzled.
// B: P-hat = P*q split into (hi,lo), streamed per (pt, kc=32) into 32KB LDS.
// dot accumulated as lo*hi + hi*lo + hi*hi chained in one f32 MFMA accumulator.
__global__ __launch_bounds__(512, 2) void screen_kernel(
    const float* __restrict__ E, const float* __restrict__ P,
    const float* __restrict__ q, int* __restrict__ out,
    int* __restrict__ wcount, int* __restrict__ wl, int wlcap) {
  __shared__ __align__(16) unsigned char ldsA[131072];  // 128 rows x 1024B ([hi 512 | lo 512])
  __shared__ __align__(16) unsigned char ldsB[32768];   // 256 protos x 128B ([hi 64 | lo 64])

  const int tid = threadIdx.x;
  const int wave = tid >> 6, lane = tid & 63;
  const int rg = wave >> 2, cg = wave & 3;
  const int g = lane >> 4, c = lane & 15;
  const int blockRow = blockIdx.x * 128;

  // ---- stage A once: E[blockRow..+128][0..256) f32 -> (hi,lo) fp16, swizzled ----
  {
    const int row = tid >> 2, qq = tid & 3;  // each thread: 64 consecutive k of one row
    const float* src = E + (size_t)(blockRow + row) * 256 + qq * 64;
    const int rswz = (row & 7) << 4;
#pragma unroll
    for (int o = 0; o < 8; ++o) {
      float4 v0 = *reinterpret_cast<const float4*>(src + o * 8);
      float4 v1 = *reinterpret_cast<const float4*>(src + o * 8 + 4);
      float e[8] = {v0.x, v0.y, v0.z, v0.w, v1.x, v1.y, v1.z, v1.w};
      f16x8 hi, lo;
#pragma unroll
      for (int t = 0; t < 8; ++t) {
        _Float16 h = (_Float16)e[t];
        hi[t] = h;
        lo[t] = (_Float16)(e[t] - (float)h);  // exact residual (Sterbenz), then rounded
      }
      const int base = row * 1024 + (qq * 64 + o * 8) * 2;
      *reinterpret_cast<f16x8*>(ldsA + (base ^ rswz)) = hi;
      *reinterpret_cast<f16x8*>(ldsA + ((base + 512) ^ rswz)) = lo;
    }
  }

  // top-2 state per lane: 16 row-slots (rows = rg*64 + fr*16 + g*4 + reg)
  float v1r[16], v2r[16];
  int i1r[16];
#pragma unroll
  for (int s = 0; s < 16; ++s) { v1r[s] = -INFINITY; v2r[s] = -INFINITY; i1r[s] = 0; }

  const int prow = tid >> 1, half = tid & 1;  // B-staging assignment (16 k per thread)
  const int pswz = (prow & 7) << 4;
  const int bbase = prow * 128 + half * 32;
  const float nanv = __builtin_nanf("");      // masked protos -> NaN (never selected by IEEE max)

  for (int pt = 0; pt < 4; ++pt) {
    const int m = pt * 256 + prow;
    const float qm = q[m];
    const float* psrc0 = P + (size_t)m * 256 + half * 16;
    // prefetch kc=0 (overlaps previous pt's fold)
    float4 pb0 = *reinterpret_cast<const float4*>(psrc0);
    float4 pb1 = *reinterpret_cast<const float4*>(psrc0 + 4);
    float4 pb2 = *reinterpret_cast<const float4*>(psrc0 + 8);
    float4 pb3 = *reinterpret_cast<const float4*>(psrc0 + 12);

    f32x4 acc[4][4];
#pragma unroll
    for (int fr = 0; fr < 4; ++fr)
#pragma unroll
      for (int fc = 0; fc < 4; ++fc) acc[fr][fc] = (f32x4){0.f, 0.f, 0.f, 0.f};

    for (int kc = 0; kc < 8; ++kc) {
      __syncthreads();  // previous readers of ldsB done
      // ---- convert + write current B chunk (hi,lo) ----
      {
        float pe[16] = {pb0.x, pb0.y, pb0.z, pb0.w, pb1.x, pb1.y, pb1.z, pb1.w,
                        pb2.x, pb2.y, pb2.z, pb2.w, pb3.x, pb3.y, pb3.z, pb3.w};
        f16x8 hi0, hi1, lo0, lo1;
#pragma unroll
        for (int t = 0; t < 8; ++t) {
          const float ph = (qm > 0.f) ? pe[t] * qm : nanv;
          const _Float16 h = (_Float16)ph;
          hi0[t] = h;
          lo0[t] = (_Float16)(ph - (float)h);
        }
#pragma unroll
        for (int t = 0; t < 8; ++t) {
          const float ph = (qm > 0.f) ? pe[8 + t] * qm : nanv;
          const _Float16 h = (_Float16)ph;
          hi1[t] = h;
          lo1[t] = (_Float16)(ph - (float)h);
        }
        *reinterpret_cast<f16x8*>(ldsB + (bbase ^ pswz)) = hi0;
        *reinterpret_cast<f16x8*>(ldsB + ((bbase + 16) ^ pswz)) = hi1;
        *reinterpret_cast<f16x8*>(ldsB + ((bbase + 64) ^ pswz)) = lo0;
        *reinterpret_cast<f16x8*>(ldsB + ((bbase + 80) ^ pswz)) = lo1;
      }
      __syncthreads();
      // prefetch next kc's B regs (hides L2 latency under MFMA)
      if (kc < 7) {
        const float* ps = psrc0 + (kc + 1) * 32;
        pb0 = *reinterpret_cast<const float4*>(ps);
        pb1 = *reinterpret_cast<const float4*>(ps + 4);
        pb2 = *reinterpret_cast<const float4*>(ps + 8);
        pb3 = *reinterpret_cast<const float4*>(ps + 12);
      }

      // ---- fragments + 3-term MFMA ----
      f16x8 ah[4], al[4], bh[4], bl[4];
#pragma unroll
      for (int fr = 0; fr < 4; ++fr) {
        const int rowA = rg * 64 + fr * 16 + c;
        const int ab = rowA * 1024 + kc * 64 + g * 16;
        const int sw = (rowA & 7) << 4;
        ah[fr] = *reinterpret_cast<const f16x8*>(ldsA + (ab ^ sw));
        al[fr] = *reinterpret_cast<const f16x8*>(ldsA + ((ab + 512) ^ sw));
      }
#pragma unroll
      for (int fc = 0; fc < 4; ++fc) {
        const int prowB = cg * 64 + fc * 16 + c;
        const int bb = prowB * 128 + g * 16;
        const int sw = (prowB & 7) << 4;
        bh[fc] = *reinterpret_cast<const f16x8*>(ldsB + (bb ^ sw));
        bl[fc] = *reinterpret_cast<const f16x8*>(ldsB + ((bb + 64) ^ sw));
      }
#pragma unroll
      for (int fr = 0; fr < 4; ++fr)
#pragma unroll
        for (int fc = 0; fc < 4; ++fc) {
          f32x4 a = acc[fr][fc];
          a = __builtin_amdgcn_mfma_f32_16x16x32_f16(al[fr], bh[fc], a, 0, 0, 0);
          a = __builtin_amdgcn_mfma_f32_16x16x32_f16(ah[fr], bl[fc], a, 0, 0, 0);
          a = __builtin_amdgcn_mfma_f32_16x16x32_f16(ah[fr], bh[fc], a, 0, 0, 0);
          acc[fr][fc] = a;
        }
    }

    // ---- fold this pt's 64 proto-columns into top-2 (full f32, strict > keeps lowest m) ----
#pragma unroll
    for (int fc = 0; fc < 4; ++fc) {
      const int mcol = pt * 256 + cg * 64 + fc * 16 + c;
#pragma unroll
      for (int fr = 0; fr < 4; ++fr)
#pragma unroll
        for (int reg = 0; reg < 4; ++reg) {
          const int s = fr * 4 + reg;
          const float v = acc[fr][fc][reg];
          const float nv1 = fmaxf(v1r[s], v);
          v2r[s] = fmaxf(v2r[s], fminf(v1r[s], v));
          i1r[s] = (v > v1r[s]) ? mcol : i1r[s];
          v1r[s] = nv1;
        }
    }
  }

  // ---- cross-lane top-2 merge over the 16 c-lanes sharing each row ----
#pragma unroll
  for (int s = 0; s < 16; ++s) {
#pragma unroll
    for (int off = 1; off <= 8; off <<= 1) {
      const float ov1 = __shfl_xor(v1r[s], off);
      const float ov2 = __shfl_xor(v2r[s], off);
      const int oi1 = __shfl_xor(i1r[s], off);
      const bool take = (ov1 > v1r[s]) || (ov1 == v1r[s] && oi1 < i1r[s]);
      const float nv2 = fmaxf(fmaxf(v2r[s], ov2), fminf(v1r[s], ov1));
      v1r[s] = fmaxf(v1r[s], ov1);
      i1r[s] = take ? oi1 : i1r[s];
      v2r[s] = nv2;
    }
  }

  __syncthreads();  // all fragment reads done -> reuse ldsB for cross-wave merge
  float* mgv1 = reinterpret_cast<float*>(ldsB);          // [128][4]
  float* mgv2 = reinterpret_cast<float*>(ldsB + 2048);   // [128][4]
  int* mgi1 = reinterpret_cast<int*>(ldsB + 4096);       // [128][4]
  if (c == 0) {
#pragma unroll
    for (int s = 0; s < 16; ++s) {
      const int row = rg * 64 + (s >> 2) * 16 + g * 4 + (s & 3);
      mgv1[row * 4 + cg] = v1r[s];
      mgv2[row * 4 + cg] = v2r[s];
      mgi1[row * 4 + cg] = i1r[s];
    }
  }
  __syncthreads();
  if (tid < 128) {
    float v1 = mgv1[tid * 4], v2 = mgv2[tid * 4];
    int i1 = mgi1[tid * 4];
#pragma unroll
    for (int w = 1; w < 4; ++w) {
      const float a1 = mgv1[tid * 4 + w], a2 = mgv2[tid * 4 + w];
      const int ai = mgi1[tid * 4 + w];
      const bool take = (a1 > v1) || (a1 == v1 && ai < i1);
      const float nv2 = fmaxf(fmaxf(v2, a2), fminf(v1, a1));
      v1 = fmaxf(v1, a1);
      i1 = take ? ai : i1;
      v2 = nv2;
    }
    const int grow = blockRow + tid;
    out[grow] = i1;
    const float margin = v1 - v2;
    if (!(margin >= TAU)) {  // NaN-safe: NaN margin -> flagged
      const int p = atomicAdd(wcount, 1);
      if (p < wlcap) wl[p] = grow;
    }
  }
}

// ---------------- kernel 3: exact f32 rescue over the worklist ----------------
// Round-1-identical accumulation per (row, proto): single ascending-k fmaf chain
// (x,y,z,w within each float4), then v = acc*q, ties to the smaller proto index.
__global__ __launch_bounds__(256) void rescue_kernel(
    const float* __restrict__ E, const float* __restrict__ P,
    const float* __restrict__ q, int* __restrict__ out,
    const int* __restrict__ wcount, const int* __restrict__ wl, int wlcap) {
  __shared__ float Elds[8][260];
  __shared__ int rowsS[8];
  __shared__ float wv[8][4];
  __shared__ int wm[8][4];

  const int tid = threadIdx.x;
  const int wave = tid >> 6, lane = tid & 63;
  int total = *wcount;
  if (total > wlcap) total = wlcap;

  for (int b0 = blockIdx.x * 8; b0 < total; b0 += gridDim.x * 8) {
    const int nb = min(8, total - b0);
    __syncthreads();
    if (tid < 8) rowsS[tid] = wl[b0 + (tid < nb ? tid : 0)];
    __syncthreads();
#pragma unroll
    for (int u = 0; u < 2; ++u) {
      const int unit = u * 256 + tid, r = unit >> 6, k4 = unit & 63;
      *reinterpret_cast<float4*>(&Elds[r][k4 * 4]) =
          *reinterpret_cast<const float4*>(E + (size_t)rowsS[r] * 256 + k4 * 4);
    }
    __syncthreads();

    float acc[8][4];  // 8 rows x 4 protos (m = tid + 256*j)
#pragma unroll
    for (int r = 0; r < 8; ++r)
#pragma unroll
      for (int j = 0; j < 4; ++j) acc[r][j] = 0.f;

#pragma unroll 2
    for (int k4 = 0; k4 < 64; ++k4) {
      float4 pv[4];
#pragma unroll
      for (int j = 0; j < 4; ++j)
        pv[j] = *reinterpret_cast<const float4*>(P + (size_t)(tid + 256 * j) * 256 + k4 * 4);
      float4 ev[8];
#pragma unroll
      for (int r = 0; r < 8; ++r) ev[r] = *reinterpret_cast<const float4*>(&Elds[r][k4 * 4]);
#pragma unroll
      for (int r = 0; r < 8; ++r)
#pragma unroll
        for (int j = 0; j < 4; ++j) {
          float a = acc[r][j];
          a = fmaf(pv[j].x, ev[r].x, a);
          a = fmaf(pv[j].y, ev[r].y, a);
          a = fmaf(pv[j].z, ev[r].z, a);
          a = fmaf(pv[j].w, ev[r].w, a);
          acc[r][j] = a;
        }
    }

    float qv[4];
#pragma unroll
    for (int j = 0; j < 4; ++j) qv[j] = q[tid + 256 * j];

#pragma unroll
    for (int r = 0; r < 8; ++r) {
      float bv = -3.0e38f;
      int bm = 0;
#pragma unroll
      for (int j = 0; j < 4; ++j) {  // m ascending -> strict > keeps lowest m
        const float v = (qv[j] > 0.f) ? acc[r][j] * qv[j] : -1.0e30f;
        if (v > bv) { bv = v; bm = tid + 256 * j; }
      }
#pragma unroll
      for (int off = 1; off <= 32; off <<= 1) {
        const float ov = __shfl_xor(bv, off);
        const int om = __shfl_xor(bm, off);
        if (ov > bv || (ov == bv && om < bm)) { bv = ov; bm = om; }
      }
      if (lane == 0) { wv[r][wave] = bv; wm[r][wave] = bm; }
    }
    __syncthreads();
    if (tid < 8) {
      float bv = wv[tid][0];
      int bm = wm[tid][0];
#pragma unroll
      for (int w = 1; w < 4; ++w) {
        const float ov = wv[tid][w];
        const int om = wm[tid][w];
        if (ov > bv || (ov == bv && om < bm)) { bv = ov; bm = om; }
      }
      if (tid < nb) out[rowsS[tid]] = bm;
    }
    __syncthreads();
  }
}

extern "C" void kernel_launch(void* const* d_in, const int* in_sizes, int n_in,
                              void* d_out, int out_size, void* d_ws, size_t ws_size,
                              hipStream_t stream) {
  const float* E = (const float*)d_in[0];
  const float* P = (const float*)d_in[1];
  const int* counts = (const int*)d_in[2];
  const int M = in_sizes[2];            // 1024
  const int Dd = in_sizes[1] / M;       // 256
  const int N = in_sizes[0] / Dd;       // 65536
  int* out = (int*)d_out;

  // workspace layout: q (4KB) | wcount (int, at +4096) | worklist (at +4224)
  float* qv = (float*)d_ws;
  int* wcount = (int*)((char*)d_ws + 4096);
  int* wl = (int*)((char*)d_ws + 4224);
  long long cap = ((long long)ws_size - 4224) / 4;
  if (cap < 0) cap = 0;
  if (cap > N) cap = N;
  int wlcap = (int)cap;

  proto_qnorm_kernel<<<M, 64, 0, stream>>>(P, counts, qv, wcount, M, Dd);
  screen_kernel<<<N / 128, 512, 0, stream>>>(E, P, qv, out, wcount, wl, wlcap);
  rescue_kernel<<<256, 256, 0, stream>>>(E, P, qv, out, wcount, wl, wlcap);
}